// Round 11
// baseline (52.205 us; speedup 1.0000x reference)
//
#include <hip/hip_runtime.h>
#include <hip/hip_bf16.h>

#define NB 16384
#define ND 1024
#define NT 20
#define NC 100
#define NTILES_MAX 532         // 32-row tiles: sum ceil(cnt_t/32) <= 531
#define STEPS 16               // K steps of BK=64
#define ABUF 8192              // 32 rows x 64 f32 x 4B
#define BBUF 14336             // 14 fragment blocks x 1KB
#define BUFB (ABUF + BBUF)     // 22528; x3 = 67584 LDS

typedef __bf16  bf16x8 __attribute__((ext_vector_type(8)));
typedef float   f32x4  __attribute__((ext_vector_type(4)));
typedef unsigned short ushort_t;

__device__ __forceinline__ unsigned int f2bf(float f) {
    unsigned int u = __builtin_bit_cast(unsigned int, f);
    u += 0x7FFFu + ((u >> 16) & 1u);   // RNE
    return u >> 16;
}
__device__ __forceinline__ unsigned long long pack4(float a, float b, float c, float d) {
    return (unsigned long long)f2bf(a)
         | ((unsigned long long)f2bf(b) << 16)
         | ((unsigned long long)f2bf(c) << 32)
         | ((unsigned long long)f2bf(d) << 48);
}
__device__ __forceinline__ bf16x8 mk_frag(float4 a, float4 b) {
    union { unsigned long long u[2]; bf16x8 v; } r;
    r.u[0] = pack4(a.x, a.y, a.z, a.w);
    r.u[1] = pack4(b.x, b.y, b.z, b.w);
    return r.v;
}

// async 16B/lane global->LDS; LDS dest = wave-uniform base + lane*16 (HW)
__device__ __forceinline__ void async_cp16(const void* g, void* l) {
    auto gp = reinterpret_cast<const __attribute__((address_space(1))) unsigned int*>(
        reinterpret_cast<unsigned long long>(g));
    auto lp = reinterpret_cast<__attribute__((address_space(3))) unsigned int*>(
        static_cast<unsigned int>(reinterpret_cast<unsigned long long>(l)));
    __builtin_amdgcn_global_load_lds(gp, lp, 16, 0, 0);
}

// ---------------- fused prep: wcvt (blocks 0..279) + bucket (block 280) -----
// Both R10-verified bodies, now concurrent (disjoint outputs).

__global__ __launch_bounds__(1024) void prep_kernel(
    const float* __restrict__ W, ushort_t* __restrict__ Wf,
    const int* __restrict__ t, int* __restrict__ offsets,
    int* __restrict__ tiles, int* __restrict__ idx_list)
{
    const int tid = threadIdx.x;
    if (blockIdx.x < 280) {
        // ---- W f32 -> bf16, MFMA-fragment-packed ----
        int g = blockIdx.x * 1024 + tid;            // 286720 threads total
        int kg   = g & 127;
        int rest = g >> 7;
        int c    = rest % 112;
        int task = rest / 112;
        unsigned long long u0 = 0, u1 = 0;
        if (c < NC) {
            const float* p = W + ((size_t)(task * NC + c)) * ND + kg * 8;
            float4 a = *(const float4*)p;
            float4 b = *(const float4*)(p + 4);
            u0 = pack4(a.x, a.y, a.z, a.w);
            u1 = pack4(b.x, b.y, b.z, b.w);
        }
        size_t dst = (((size_t)task * 32 + (kg >> 2)) * 7 + (c >> 4)) * 512
                   + (size_t)((c & 15) | ((kg & 3) << 4)) * 8;
        *(unsigned long long*)(Wf + dst)     = u0;
        *(unsigned long long*)(Wf + dst + 4) = u1;
        return;
    }
    // ---- bucketing (single block) ----
    __shared__ int h[NT], off[NT + 1], cur[NT], tb[NT + 1];
    if (tid < NT) h[tid] = 0;
    __syncthreads();
    const int4* t4 = (const int4*)t;
    int4 v[4];
#pragma unroll
    for (int k = 0; k < 4; ++k) v[k] = t4[tid + k * 1024];
#pragma unroll
    for (int k = 0; k < 4; ++k) {
        atomicAdd(&h[v[k].x], 1); atomicAdd(&h[v[k].y], 1);
        atomicAdd(&h[v[k].z], 1); atomicAdd(&h[v[k].w], 1);
    }
    __syncthreads();
    if (tid == 0) {
        int acc = 0, tv = 0;
        for (int i = 0; i < NT; ++i) {
            off[i] = acc; cur[i] = acc; tb[i] = tv;
            acc += h[i]; tv += (h[i] + 31) >> 5;
        }
        off[NT] = acc; tb[NT] = tv;
    }
    __syncthreads();
    if (tid <= NT) offsets[tid] = off[tid];
    const int ntiles = tb[NT];
    for (int g = tid; g < NTILES_MAX; g += 1024) {
        int e = -1;
        if (g < ntiles) {
            int task = 0;
            while (tb[task + 1] <= g) ++task;
            e = (task << 16) | (g - tb[task]);
        }
        tiles[g] = e;
    }
#pragma unroll
    for (int k = 0; k < 4; ++k) {
        int base = (tid + k * 1024) * 4;
        idx_list[atomicAdd(&cur[v[k].x], 1)] = base;
        idx_list[atomicAdd(&cur[v[k].y], 1)] = base + 1;
        idx_list[atomicAdd(&cur[v[k].z], 1)] = base + 2;
        idx_list[atomicAdd(&cur[v[k].w], 1)] = base + 3;
    }
}

// ---------------- grouped GEMM: R10-verified skeleton, triple-buffered ------
// Block = 32 rows x 112 cols x K=1024. Per step: stage A (8x1KB async,
// inverse-swizzled f32 source) + B (14x1KB async, fragment-packed, linear).
// 3 LDS buffers; STAGE(s+3) fills the buffer COMPUTE(s) just drained.
// vmcnt(12) => stage s+1 landed (2 step-times of slack, ~12KB/wave in flight).

__global__ __launch_bounds__(256, 2) void gemm_kernel(
    const float* __restrict__ x, const ushort_t* __restrict__ Wfrag,
    const float* __restrict__ bias, const int* __restrict__ offsets,
    const int* __restrict__ tiles, const int* __restrict__ idx_list,
    float* __restrict__ out)
{
    __shared__ __align__(16) char lds[3 * BUFB];
    const int ent = tiles[blockIdx.x];
    if (ent < 0) return;
    const int task = ent >> 16;
    const int m0   = (ent & 0xffff) << 5;
    const int seg  = offsets[task];
    const int cnt  = offsets[task + 1] - seg;

    const int tid  = threadIdx.x;
    const int wid  = tid >> 6;
    const int lane = tid & 63;
    const int wm   = wid >> 1;          // row-group
    const int wn   = wid & 1;           // frag-group
    const int csel = lane & 15;
    const int q    = lane >> 4;

    // A staging sources: instr j = 2*wid + jj covers rows j*4..j*4+3
    const float* srcA[2];
#pragma unroll
    for (int jj = 0; jj < 2; ++jj) {
        int j    = 2 * wid + jj;
        int row  = j * 4 + q;
        int byte = csel * 16;
        int logb = byte ^ ((row & 7) << 4);     // inverse-swizzled source
        int sr   = m0 + row; if (sr > cnt - 1) sr = cnt - 1;
        srcA[jj] = x + (size_t)idx_list[seg + sr] * ND + (logb >> 2);
    }
    // B staging: fragment-packed, lane-linear source; slots ii = kkb*7+frag
    const ushort_t* srcB = Wfrag + (size_t)task * (32 * 7 * 512) + lane * 8;
    int bii[4];
#pragma unroll
    for (int jj = 0; jj < 4; ++jj) {
        int i = wid + 4 * jj;
        bii[jj] = (i < 14) ? i : (i - 14);   // 2 dup stages: identical data, benign
    }

    auto STAGE = [&](int s, char* Ab) {
        char* Bb = Ab + ABUF;
        async_cp16(srcA[0] + s * 64, Ab + (2 * wid + 0) * 1024);
        async_cp16(srcA[1] + s * 64, Ab + (2 * wid + 1) * 1024);
#pragma unroll
        for (int jj = 0; jj < 4; ++jj)
            async_cp16(srcB + (size_t)(s * 14 + bii[jj]) * 512, Bb + bii[jj] * 1024);
    };

    const int rowA = wm * 16 + csel;
    const unsigned swzA = (unsigned)((rowA & 7) << 4);
    const int nfr = wn ? 3 : 4;
    f32x4 acc[4] = {};

    auto COMPUTE = [&](const char* Ab) {
        const char* Bb = Ab + ABUF;
        const char* Ar = Ab + rowA * 256;
#pragma unroll
        for (int kkb = 0; kkb < 2; ++kkb) {
            unsigned abase = (unsigned)(kkb * 128 + q * 32);
            float4 a0 = *(const float4*)(Ar + (abase ^ swzA));
            float4 a1 = *(const float4*)(Ar + ((abase + 16) ^ swzA));
            bf16x8 af = mk_frag(a0, a1);
#pragma unroll
            for (int nf = 0; nf < 4; ++nf) {
                if (nf < nfr) {
                    int f = wn * 4 + nf;
                    bf16x8 bf = *(const bf16x8*)(Bb + (kkb * 7 + f) * 1024 + lane * 16);
                    acc[nf] = __builtin_amdgcn_mfma_f32_16x16x32_bf16(af, bf, acc[nf], 0, 0, 0);
                }
            }
        }
    };

    // prologue: 3 stages in flight, wait for stage 0 only (6 instrs x 3 /wave)
    STAGE(0, lds);
    STAGE(1, lds + BUFB);
    STAGE(2, lds + 2 * BUFB);
    asm volatile("s_waitcnt vmcnt(12)" ::: "memory");   // my STAGE(0) landed
    __builtin_amdgcn_sched_barrier(0);
    __builtin_amdgcn_s_barrier();                       // everyone's STAGE(0) landed

    int bufc = 0;                        // buffer holding step s
#pragma unroll 1
    for (int s = 0; s < STEPS; ++s) {
        char* Ab = lds + bufc * BUFB;
        COMPUTE(Ab);
        if (s == STEPS - 1) break;
        asm volatile("s_waitcnt lgkmcnt(0)" ::: "memory");   // my buf-s reads done
        __builtin_amdgcn_s_barrier();                        // all buf-s reads done
        if (s < STEPS - 3) {
            STAGE(s + 3, Ab);                                // refill drained buffer
            asm volatile("s_waitcnt vmcnt(12)" ::: "memory");// stage s+1 landed
        } else if (s == STEPS - 3) {
            asm volatile("s_waitcnt vmcnt(6)" ::: "memory"); // stage s+1 landed
        } else {
            asm volatile("s_waitcnt vmcnt(0)" ::: "memory"); // stage s+1 landed
        }
        __builtin_amdgcn_sched_barrier(0);
        __builtin_amdgcn_s_barrier();
        bufc = (bufc == 2) ? 0 : bufc + 1;
    }

    // epilogue: direct store + bias
    int oi[4];
#pragma unroll
    for (int rr = 0; rr < 4; ++rr) {
        int gm = m0 + wm * 16 + q * 4 + rr;
        oi[rr] = (gm < cnt) ? idx_list[seg + gm] : -1;
    }
#pragma unroll
    for (int nf = 0; nf < 4; ++nf) {
        if (nf < nfr) {
            int cg = (wn * 4 + nf) * 16 + csel;
            if (cg < NC) {
                float bv = bias[task * NC + cg];
#pragma unroll
                for (int rr = 0; rr < 4; ++rr)
                    if (oi[rr] >= 0)
                        out[(size_t)oi[rr] * NC + cg] = acc[nf][rr] + bv;
            }
        }
    }
}

// ---------------- launch ----------------

extern "C" void kernel_launch(void* const* d_in, const int* in_sizes, int n_in,
                              void* d_out, int out_size, void* d_ws, size_t ws_size,
                              hipStream_t stream) {
    const float* x    = (const float*)d_in[0];
    const int*   t    = (const int*)d_in[1];
    const float* W    = (const float*)d_in[2];
    const float* bias = (const float*)d_in[3];

    char* ws = (char*)d_ws;
    int* offsets  = (int*)ws;                    // 21 ints  @ 0
    int* tiles    = (int*)(ws + 128);            // 532 ints -> ends 2256
    int* idx_list = (int*)(ws + 4352);           // 16384 ints -> ends 69888
    ushort_t* Wf  = (ushort_t*)(ws + 69888);     // 4,587,520 B

    prep_kernel<<<281, 1024, 0, stream>>>(W, Wf, t, offsets, tiles, idx_list);
    gemm_kernel<<<NTILES_MAX, 256, 0, stream>>>(x, Wf, bias, offsets, tiles,
                                                idx_list, (float*)d_out);
}